// Round 1
// baseline (59.141 us; speedup 1.0000x reference)
//
#include <hip/hip_runtime.h>

// RandomFilter: per-image 3x3 depthwise correlation with impulse at [2,2].
// img: [32, 3, 512, 512] fp32; noise: [32, 3, 3] fp32.
// out[b,c,h,w] = clip( sum_{kh,kw} img_pad[b,c,h+kh-1,w+kw-1] * W[b,kh,kw], 0, 1 )
// where W[b] = 0.1*noise[b] + delta(2,2).  SAME padding (pad=1).
// Memory-bound: ~201 MB total traffic -> ~32 us roofline @ 6.3 TB/s.

#define RF_H 512
#define RF_W 512
#define RF_C 3
#define RF_B 32
#define RF_SIGMA 0.1f

__global__ __launch_bounds__(256) void RandomFilter_40767829574170_kernel(
    const float* __restrict__ img,
    const float* __restrict__ noise,
    float* __restrict__ out,
    int n4)   // total float4 groups = B*C*H*W/4
{
    const int W4 = RF_W / 4;  // 128 float4 per row
    const long long stride = (long long)gridDim.x * blockDim.x;
    for (long long g = (long long)blockIdx.x * blockDim.x + threadIdx.x; g < n4;
         g += stride) {
        const int w4    = (int)(g & (W4 - 1));          // W4 = 128, pow2
        const int h     = (int)((g >> 7) & (RF_H - 1)); // /128 % 512
        const int plane = (int)(g >> 16);               // /(128*512) = b*C + c
        const int b     = plane / RF_C;

        // Build the 3x3 weight from noise (uniform per block -> L1 broadcast).
        const float* np_ = noise + b * 9;
        float wgt[3][3];
        #pragma unroll
        for (int r = 0; r < 3; ++r) {
            #pragma unroll
            for (int s = 0; s < 3; ++s) {
                wgt[r][s] = RF_SIGMA * np_[r * 3 + s];
            }
        }
        wgt[2][2] += 1.0f;  // delta impulse at [2,2] (center = ceil(K/2))

        const float* plane_ptr = img + (long long)plane * (RF_H * RF_W);
        const int w0 = w4 * 4;

        float acc0 = 0.f, acc1 = 0.f, acc2 = 0.f, acc3 = 0.f;
        #pragma unroll
        for (int r = 0; r < 3; ++r) {
            const int hr = h + r - 1;
            if (hr < 0 || hr >= RF_H) continue;  // zero padding rows
            const float* row = plane_ptr + hr * RF_W;
            const float4 mid = *reinterpret_cast<const float4*>(row + w0);
            float v0 = (w0 > 0)          ? row[w0 - 1] : 0.0f;  // left pad
            float v5 = (w0 + 4 < RF_W)   ? row[w0 + 4] : 0.0f;  // right pad
            const float k0 = wgt[r][0], k1 = wgt[r][1], k2 = wgt[r][2];
            acc0 += k0 * v0    + k1 * mid.x + k2 * mid.y;
            acc1 += k0 * mid.x + k1 * mid.y + k2 * mid.z;
            acc2 += k0 * mid.y + k1 * mid.z + k2 * mid.w;
            acc3 += k0 * mid.z + k1 * mid.w + k2 * v5;
        }

        float4 o;
        o.x = acc0; o.y = acc1; o.z = acc2; o.w = acc3;
        float* op = &o.x;
        #pragma unroll
        for (int j = 0; j < 4; ++j) {
            float y = op[j];
            y = isnan(y) ? 1.0f : y;          // reference's nan -> 1.0
            y = fminf(fmaxf(y, 0.0f), 1.0f);  // clip to [0,1]
            op[j] = y;
        }
        *reinterpret_cast<float4*>(out + g * 4) = o;
    }
}

extern "C" void kernel_launch(void* const* d_in, const int* in_sizes, int n_in,
                              void* d_out, int out_size, void* d_ws, size_t ws_size,
                              hipStream_t stream) {
    const float* img   = (const float*)d_in[0];
    const float* noise = (const float*)d_in[1];
    float* out = (float*)d_out;

    const int n4 = out_size / 4;  // 6,291,456 float4 groups
    const int block = 256;
    // Cap grid at full-residency (256 CU x 8 blocks of 4 waves) and grid-stride.
    int grid = (n4 + block - 1) / block;
    if (grid > 2048) grid = 2048;
    RandomFilter_40767829574170_kernel<<<grid, block, 0, stream>>>(img, noise, out, n4);
}

// Round 2
// 39.492 us; speedup vs baseline: 1.4975x; 1.4975x over previous
//
#include <hip/hip_runtime.h>

// RandomFilter: per-image 3x3 depthwise correlation, impulse at [2,2] (shift +1,+1).
// img: [32, 3, 512, 512] fp32; noise: [32, 3, 3] fp32.
// out[b,c,h,w] = clip( sum img_pad[h+kh-1][w+kw-1] * (0.1*noise[b] + delta22)[kh][kw], 0, 1 )
//
// R2 structure: thread = 4-row x 4-col output tile. 6 input rows loaded once into
// registers, 16 outputs computed -> 3x fewer load instructions per output, weight
// build amortized 4x, no grid-stride loop.

#define RF_H 512
#define RF_W 512
#define RF_C 3
#define RF_PLANES 96          // 32 images * 3 channels
#define RF_SIGMA 0.1f
#define RF_W4 128             // float4 groups per row
#define RF_STRIPS 128         // 4-row strips per plane

__global__ __launch_bounds__(256) void RandomFilter_40767829574170_kernel(
    const float* __restrict__ img,
    const float* __restrict__ noise,
    float* __restrict__ out)
{
    const int idx   = blockIdx.x * 256 + threadIdx.x;
    const int w4    = idx & (RF_W4 - 1);          // 0..127
    const int strip = (idx >> 7) & (RF_STRIPS - 1);
    const int plane = idx >> 14;                  // 0..95, uniform per block
    const int b     = plane / RF_C;

    // Build 3x3 weight (9 uniform loads -> L1 broadcast; once per 16 outputs).
    const float* np_ = noise + b * 9;
    float wgt[3][3];
    #pragma unroll
    for (int r = 0; r < 3; ++r)
        #pragma unroll
        for (int s = 0; s < 3; ++s)
            wgt[r][s] = RF_SIGMA * np_[r * 3 + s];
    wgt[2][2] += 1.0f;  // delta impulse at [2,2] (center = ceil(K/2))

    const float* P  = img + plane * (RF_H * RF_W);
    const int    w0 = w4 * 4;
    const int    h0 = strip * 4;

    // Load 6 input rows (h0-1 .. h0+4), each as [left, m0..m3, right].
    float L[6][6];
    #pragma unroll
    for (int r = 0; r < 6; ++r) {
        const int hr = h0 - 1 + r;
        if (hr < 0 || hr >= RF_H) {
            #pragma unroll
            for (int j = 0; j < 6; ++j) L[r][j] = 0.0f;
        } else {
            const float* row = P + (hr << 9);
            const float4 m = *reinterpret_cast<const float4*>(row + w0);
            L[r][1] = m.x; L[r][2] = m.y; L[r][3] = m.z; L[r][4] = m.w;
            L[r][0] = (w0 > 0)            ? row[w0 - 1] : 0.0f;
            L[r][5] = (w0 + 4 < RF_W)     ? row[w0 + 4] : 0.0f;
        }
    }

    float* outP = out + plane * (RF_H * RF_W) + w0;
    #pragma unroll
    for (int o = 0; o < 4; ++o) {
        float a0 = 0.f, a1 = 0.f, a2 = 0.f, a3 = 0.f;
        #pragma unroll
        for (int r = 0; r < 3; ++r) {
            const float k0 = wgt[r][0], k1 = wgt[r][1], k2 = wgt[r][2];
            a0 += k0 * L[o + r][0] + k1 * L[o + r][1] + k2 * L[o + r][2];
            a1 += k0 * L[o + r][1] + k1 * L[o + r][2] + k2 * L[o + r][3];
            a2 += k0 * L[o + r][2] + k1 * L[o + r][3] + k2 * L[o + r][4];
            a3 += k0 * L[o + r][3] + k1 * L[o + r][4] + k2 * L[o + r][5];
        }
        float4 ov;
        float* op = &ov.x;
        float  av[4] = {a0, a1, a2, a3};
        #pragma unroll
        for (int j = 0; j < 4; ++j) {
            float y = av[j];
            y = isnan(y) ? 1.0f : y;          // reference nan -> 1.0
            y = fminf(fmaxf(y, 0.0f), 1.0f);  // clip (v_med3 idiom)
            op[j] = y;
        }
        *reinterpret_cast<float4*>(outP + ((h0 + o) << 9)) = ov;
    }
}

extern "C" void kernel_launch(void* const* d_in, const int* in_sizes, int n_in,
                              void* d_out, int out_size, void* d_ws, size_t ws_size,
                              hipStream_t stream) {
    const float* img   = (const float*)d_in[0];
    const float* noise = (const float*)d_in[1];
    float* out = (float*)d_out;

    // 96 planes * 128 strips * 128 w-groups = 1,572,864 threads = 6144 blocks
    const int grid = RF_PLANES * RF_STRIPS * RF_W4 / 256;
    RandomFilter_40767829574170_kernel<<<grid, 256, 0, stream>>>(img, noise, out);
}